// Round 5
// baseline (236.157 us; speedup 1.0000x reference)
//
#include <hip/hip_runtime.h>
#include <hip/hip_bf16.h>

#define IRREPS 240
#define ROWPAD 256   // bf16 elements per permuted row = 512 B (line-aligned)
#define NPB 4        // nodes per block in phase B (one per wave)

// ---------- CSR build ----------
__global__ void histogram_kernel(const int* __restrict__ eidx, int* __restrict__ counts,
                                 int n_edges) {
    int e = blockIdx.x * blockDim.x + threadIdx.x;
    if (e >= n_edges) return;
    int2 p = reinterpret_cast<const int2*>(eidx)[e];
    atomicAdd(&counts[p.y], 1);
}

__global__ void scan_kernel(const int* __restrict__ counts, int* __restrict__ offsets,
                            int* __restrict__ cursor, int n) {
    __shared__ int part[1024];
    int t = threadIdx.x;
    int per = (n + 1023) / 1024;
    int start = t * per;
    int end = min(start + per, n);
    int sum = 0;
    for (int i = start; i < end; ++i) sum += counts[i];
    part[t] = sum;
    __syncthreads();
    for (int off = 1; off < 1024; off <<= 1) {
        int v = (t >= off) ? part[t - off] : 0;
        __syncthreads();
        part[t] += v;
        __syncthreads();
    }
    int run = (t == 0) ? 0 : part[t - 1];
    for (int i = start; i < end; ++i) {
        offsets[i] = run;
        cursor[i] = run;
        run += counts[i];
    }
}

// inverse permutation: slot[e] = destination row of edge e in CSR order
__global__ void fill_slot_kernel(const int* __restrict__ eidx, int* __restrict__ cursor,
                                 int* __restrict__ slot, int n_edges) {
    int e = blockIdx.x * blockDim.x + threadIdx.x;
    if (e >= n_edges) return;
    int2 p = reinterpret_cast<const int2*>(eidx)[e];
    slot[e] = atomicAdd(&cursor[p.y], 1);
}

// ---------- phase A: streaming read, weighted bf16 convert, permuted write ----------
// Block = 256 = 4 waves, wave handles one edge: lanes 0..59 carry float4 of the row,
// lanes 60..63 write zero padding so every 64B line of the 512B row is fully written.
__global__ void permute_kernel(const float* __restrict__ msgs,
                               const float* __restrict__ cutoff,
                               const int* __restrict__ slot,
                               __hip_bfloat16* __restrict__ perm,
                               int n_edges) {
    int t = threadIdx.x;
    int w = t >> 6;
    int lane = t & 63;
    int e = blockIdx.x * 4 + w;
    if (e >= n_edges) return;

    int pos = slot[e];       // wave-uniform
    float wt = cutoff[e];    // wave-uniform

    union { __hip_bfloat16 h[4]; uint2 u; } pk;
    if (lane < 60) {
        const float4 m = *reinterpret_cast<const float4*>(
            msgs + (size_t)e * IRREPS + lane * 4);
        pk.h[0] = __float2bfloat16(m.x * wt);
        pk.h[1] = __float2bfloat16(m.y * wt);
        pk.h[2] = __float2bfloat16(m.z * wt);
        pk.h[3] = __float2bfloat16(m.w * wt);
    } else {
        pk.u = make_uint2(0u, 0u);
    }
    *reinterpret_cast<uint2*>(perm + (size_t)pos * ROWPAD + lane * 4) = pk.u;
}

// ---------- phase B: streaming segment-sum + fused equivariant linear ----------
__global__ void reduce_linear_kernel(const __hip_bfloat16* __restrict__ perm,
                                     const int* __restrict__ offsets,
                                     const int* __restrict__ counts,
                                     const float* __restrict__ W0,
                                     const float* __restrict__ W1,
                                     const float* __restrict__ W2,
                                     float* __restrict__ out,
                                     int n_nodes) {
    __shared__ float s_node[NPB][IRREPS];

    int t = threadIdx.x;
    int w = t >> 6;
    int lane = t & 63;
    int n = blockIdx.x * NPB + w;

    float4 acc = make_float4(0.f, 0.f, 0.f, 0.f);

    if (n < n_nodes) {
        int beg = offsets[n];
        int cnt = counts[n];
        const __hip_bfloat16* base = perm + (size_t)beg * ROWPAD + lane * 4;
        #pragma unroll 8
        for (int j = 0; j < cnt; ++j) {
            uint2 u = *reinterpret_cast<const uint2*>(base + (size_t)j * ROWPAD);
            acc.x += __uint_as_float(u.x << 16);
            acc.y += __uint_as_float(u.x & 0xffff0000u);
            acc.z += __uint_as_float(u.y << 16);
            acc.w += __uint_as_float(u.y & 0xffff0000u);
        }
    }

    if (n < n_nodes && lane < 60) {
        *reinterpret_cast<float4*>(&s_node[w][lane * 4]) = acc;
    }
    __syncthreads();

    for (int j = 0; j < NPB; ++j) {
        int nd = blockIdx.x * NPB + j;
        if (nd >= n_nodes) break;
        if (t < IRREPS) {
            const float* s = s_node[j];
            float a = 0.f;
            float res;
            if (t < 64) {
                int o = t;
                #pragma unroll 8
                for (int i = 0; i < 64; ++i) a += W0[o * 64 + i] * s[i];
                res = a * 0.125f;               // 1/sqrt(64)
            } else if (t < 160) {
                int rel = t - 64;
                int o = rel / 3, d = rel % 3;
                #pragma unroll 8
                for (int i = 0; i < 32; ++i) a += W1[o * 32 + i] * s[64 + i * 3 + d];
                res = a * 0.17677669529663687f; // 1/sqrt(32)
            } else {
                int rel = t - 160;
                int o = rel / 5, d = rel % 5;
                #pragma unroll
                for (int i = 0; i < 16; ++i) a += W2[o * 16 + i] * s[160 + i * 5 + d];
                res = a * 0.25f;                // 1/sqrt(16)
            }
            out[(size_t)nd * IRREPS + t] = res;
        }
    }
}

extern "C" void kernel_launch(void* const* d_in, const int* in_sizes, int n_in,
                              void* d_out, int out_size, void* d_ws, size_t ws_size,
                              hipStream_t stream) {
    const float* msgs   = (const float*)d_in[0];
    const int*   eidx   = (const int*)d_in[1];
    const float* cutoff = (const float*)d_in[2];
    const float* W0     = (const float*)d_in[3];
    const float* W1     = (const float*)d_in[4];
    const float* W2     = (const float*)d_in[5];

    int n_edges = in_sizes[0] / IRREPS;
    int n_nodes = out_size / IRREPS;

    // workspace layout
    int* counts  = (int*)d_ws;
    int* offsets = counts + n_nodes;
    int* cursor  = offsets + n_nodes;
    int* slot    = cursor + n_nodes;
    size_t intbytes = ((size_t)3 * n_nodes + (size_t)n_edges) * sizeof(int);
    size_t permoff = (intbytes + 511) & ~(size_t)511;
    __hip_bfloat16* perm = (__hip_bfloat16*)((char*)d_ws + permoff);

    hipMemsetAsync(counts, 0, (size_t)n_nodes * sizeof(int), stream);

    int block = 256;
    int egrid = (n_edges + block - 1) / block;
    histogram_kernel<<<egrid, block, 0, stream>>>(eidx, counts, n_edges);
    scan_kernel<<<1, 1024, 0, stream>>>(counts, offsets, cursor, n_nodes);
    fill_slot_kernel<<<egrid, block, 0, stream>>>(eidx, cursor, slot, n_edges);

    int pgrid = (n_edges + 3) / 4;
    permute_kernel<<<pgrid, 256, 0, stream>>>(msgs, cutoff, slot, perm, n_edges);

    int ngrid = (n_nodes + NPB - 1) / NPB;
    reduce_linear_kernel<<<ngrid, 256, 0, stream>>>(
        perm, offsets, counts, W0, W1, W2, (float*)d_out, n_nodes);
}